// Round 3
// baseline (63.703 us; speedup 1.0000x reference)
//
#include <hip/hip_runtime.h>

#define N_SAMPLES 32768
#define N_EVENTS 16
#define HOP 256

typedef float f32x4 __attribute__((ext_vector_type(4)));

// Each block: batch b, complementary span pair (p, 7-p); spans are 4096 samples.
// Each wave owns 1024 consecutive samples of each span, processed as 4 chunks
// of 256 floats (1 KB per wave-load). Event-outer / chunk-inner ordering makes
// each event-row stream a 4 KB contiguous back-to-back run (DRAM page-friendly)
// instead of 1 KB interleaved.
__global__ __launch_bounds__(256) void ola_gather_kernel(
    const float* __restrict__ x,     // (128, 16, 32768)
    const int* __restrict__ indices, // (128, 16)
    float* __restrict__ out)         // (128, 32768)
{
    const int p    = blockIdx.x >> 7;   // 0..3  (span pair)
    const int b    = blockIdx.x & 127;  // 0..127
    const int wave = threadIdx.x >> 6;  // 0..3
    const int lane = threadIdx.x & 63;

    const int baseA = p * 4096 + wave * 1024;        // spans 0..3
    const int baseB = (7 - p) * 4096 + wave * 1024;  // spans 7..4

    const float* xb = x + (size_t)b * N_EVENTS * N_SAMPLES;
    const int*   ib = indices + b * N_EVENTS;

    f32x4 aA[4] = {(f32x4)0.f, (f32x4)0.f, (f32x4)0.f, (f32x4)0.f};
    f32x4 aB[4] = {(f32x4)0.f, (f32x4)0.f, (f32x4)0.f, (f32x4)0.f};

#pragma unroll
    for (int i = 0; i < N_EVENTS; ++i) {
        const int start = ib[i] * HOP;  // multiple of 256, wave-uniform
        const float* row = xb + (size_t)i * N_SAMPLES;
#pragma unroll
        for (int c = 0; c < 4; ++c) {
            const int sA = baseA + c * 256;
            if (sA >= start) {  // uniform per chunk (start % 256 == 0)
                aA[c] += __builtin_nontemporal_load(
                    reinterpret_cast<const f32x4*>(row + (sA - start) + lane * 4));
            }
        }
#pragma unroll
        for (int c = 0; c < 4; ++c) {
            const int sB = baseB + c * 256;
            if (sB >= start) {
                aB[c] += __builtin_nontemporal_load(
                    reinterpret_cast<const f32x4*>(row + (sB - start) + lane * 4));
            }
        }
    }

    float* ob = out + (size_t)b * N_SAMPLES;
#pragma unroll
    for (int c = 0; c < 4; ++c)
        __builtin_nontemporal_store(aA[c],
            reinterpret_cast<f32x4*>(ob + baseA + c * 256 + lane * 4));
#pragma unroll
    for (int c = 0; c < 4; ++c)
        __builtin_nontemporal_store(aB[c],
            reinterpret_cast<f32x4*>(ob + baseB + c * 256 + lane * 4));
}

extern "C" void kernel_launch(void* const* d_in, const int* in_sizes, int n_in,
                              void* d_out, int out_size, void* d_ws, size_t ws_size,
                              hipStream_t stream) {
    const float* x       = (const float*)d_in[0];
    const int*   indices = (const int*)d_in[1];
    float*       out     = (float*)d_out;

    // 128 batches * 4 span-pairs = 512 blocks
    ola_gather_kernel<<<512, 256, 0, stream>>>(x, indices, out);
}

// Round 4
// 29.715 us; speedup vs baseline: 2.1438x; 2.1438x over previous
//
#include <hip/hip_runtime.h>

#define N_SAMPLES 32768
#define N_EVENTS 16
#define HOP 256
#define TILE 1024   // samples per block = 256 threads * 4

typedef float f32x4 __attribute__((ext_vector_type(4)));

__global__ __launch_bounds__(256) void ola_gather_kernel(
    const float* __restrict__ x,     // (128, 16, 32768)
    const int* __restrict__ indices, // (128, 16)
    float* __restrict__ out)         // (128, 32768)
{
    const int tile = blockIdx.x & 31;        // 32 tiles per batch
    const int b    = blockIdx.x >> 5;
    const int s0   = tile * TILE + threadIdx.x * 4;

    const float* xb = x + (size_t)b * N_EVENTS * N_SAMPLES;
    const int*   ib = indices + b * N_EVENTS;

    // Phase 1: issue ALL 16 loads unconditionally (clamped offset keeps each
    // load inside its own row), so 16 independent global_load_dwordx4 are in
    // flight per thread before any accumulate waits on them.
    f32x4 vals[N_EVENTS];
    int   offs[N_EVENTS];
#pragma unroll
    for (int i = 0; i < N_EVENTS; ++i) {
        const int off = s0 - ib[i] * HOP;    // start is a multiple of 256
        offs[i] = off;
        const int offc = off > 0 ? off : 0;  // clamped: always in [0, N-4]
        // NOT nontemporal: masked (clamped) repeats of each row's first 1 KB
        // must be cache-absorbed, not sent to HBM.
        vals[i] = *reinterpret_cast<const f32x4*>(
            xb + (size_t)i * N_SAMPLES + offc);
    }

    // Phase 2: branchless masked accumulate (v_cndmask + v_add).
    f32x4 acc = (f32x4)0.f;
#pragma unroll
    for (int i = 0; i < N_EVENTS; ++i) {
        acc += (offs[i] >= 0) ? vals[i] : (f32x4)0.f;
    }

    __builtin_nontemporal_store(acc,
        reinterpret_cast<f32x4*>(out + (size_t)b * N_SAMPLES + s0));
}

extern "C" void kernel_launch(void* const* d_in, const int* in_sizes, int n_in,
                              void* d_out, int out_size, void* d_ws, size_t ws_size,
                              hipStream_t stream) {
    const float* x       = (const float*)d_in[0];
    const int*   indices = (const int*)d_in[1];
    float*       out     = (float*)d_out;

    // 128 batches * 32 tiles = 4096 blocks
    const int blocks = 128 * (N_SAMPLES / TILE);
    ola_gather_kernel<<<blocks, 256, 0, stream>>>(x, indices, out);
}

// Round 5
// 28.759 us; speedup vs baseline: 2.2151x; 1.0333x over previous
//
#include <hip/hip_runtime.h>

#define N_SAMPLES 32768
#define N_EVENTS 16
#define HOP 256
#define TILE 1024   // samples per tile = 256 threads * 4 floats

typedef float f32x4 __attribute__((ext_vector_type(4)));

__global__ __launch_bounds__(256) void ola_gather_kernel(
    const float* __restrict__ x,     // (128, 16, 32768)
    const int* __restrict__ indices, // (128, 16)
    float* __restrict__ out)         // (128, 32768)
{
    const int b = blockIdx.x & 127;  // batch
    const int p = blockIdx.x >> 7;   // 0..15 -> tile pair (p, 31-p)

    const float* xb = x + (size_t)b * N_EVENTS * N_SAMPLES;
    float*       ob = out + (size_t)b * N_SAMPLES;
    const int*   ib = indices + b * N_EVENTS;

    // Wave-uniform starts (scalar loads), multiples of 256.
    int start[N_EVENTS];
#pragma unroll
    for (int i = 0; i < N_EVENTS; ++i) start[i] = ib[i] * HOP;

    // Two complementary tiles per block: uniform total work per block and
    // 2x work per wave (halves dispatch/drain ramp share).
#pragma unroll
    for (int half = 0; half < 2; ++half) {
        const int tile = half ? (31 - p) : p;
        const int s0   = tile * TILE + threadIdx.x * 4;

        // Issue ALL 16 loads unconditionally (clamped offsets stay in-row),
        // then mask on accumulate: 16 independent dwordx4 in flight.
        f32x4 vals[N_EVENTS];
        int   offs[N_EVENTS];
#pragma unroll
        for (int i = 0; i < N_EVENTS; ++i) {
            const int off = s0 - start[i];
            offs[i] = off;
            const int offc = off > 0 ? off : 0;
            vals[i] = *reinterpret_cast<const f32x4*>(
                xb + (size_t)i * N_SAMPLES + offc);
        }

        f32x4 acc = (f32x4)0.f;
#pragma unroll
        for (int i = 0; i < N_EVENTS; ++i) {
            acc += (offs[i] >= 0) ? vals[i] : (f32x4)0.f;
        }

        __builtin_nontemporal_store(acc, reinterpret_cast<f32x4*>(ob + s0));
    }
}

extern "C" void kernel_launch(void* const* d_in, const int* in_sizes, int n_in,
                              void* d_out, int out_size, void* d_ws, size_t ws_size,
                              hipStream_t stream) {
    const float* x       = (const float*)d_in[0];
    const int*   indices = (const int*)d_in[1];
    float*       out     = (float*)d_out;

    // 128 batches * 16 tile-pairs = 2048 blocks
    ola_gather_kernel<<<2048, 256, 0, stream>>>(x, indices, out);
}

// Round 6
// 28.428 us; speedup vs baseline: 2.2409x; 1.0116x over previous
//
#include <hip/hip_runtime.h>

#define N_SAMPLES 32768
#define N_EVENTS 16
#define HOP 256
#define TILE 1024   // samples per tile = 256 threads * 4 floats

typedef float f32x4 __attribute__((ext_vector_type(4)));

__global__ __launch_bounds__(256) void ola_gather_kernel(
    const float* __restrict__ x,     // (128, 16, 32768)
    const int* __restrict__ indices, // (128, 16)
    float* __restrict__ out)         // (128, 32768)
{
    const int b = blockIdx.x & 127;  // batch
    const int p = blockIdx.x >> 7;   // 0..7 -> tile quad {p, 15-p, 16+p, 31-p}

    const float* xb = x + (size_t)b * N_EVENTS * N_SAMPLES;
    float*       ob = out + (size_t)b * N_SAMPLES;
    const int*   ib = indices + b * N_EVENTS;

    // Wave-uniform starts (scalar loads), multiples of 256.
    int start[N_EVENTS];
#pragma unroll
    for (int i = 0; i < N_EVENTS; ++i) start[i] = ib[i] * HOP;

    // Four tiles per block with constant total work:
    // sum of tile indices = p + (15-p) + (16+p) + (31-p) = 62 for every p.
    const int tiles[4] = {p, 15 - p, 16 + p, 31 - p};

#pragma unroll
    for (int t = 0; t < 4; ++t) {
        const int s0 = tiles[t] * TILE + threadIdx.x * 4;

        // Issue ALL 16 loads unconditionally (clamped offsets stay in-row),
        // then mask on accumulate: 16 independent dwordx4 in flight.
        f32x4 vals[N_EVENTS];
        int   offs[N_EVENTS];
#pragma unroll
        for (int i = 0; i < N_EVENTS; ++i) {
            const int off = s0 - start[i];
            offs[i] = off;
            const int offc = off > 0 ? off : 0;
            vals[i] = *reinterpret_cast<const f32x4*>(
                xb + (size_t)i * N_SAMPLES + offc);
        }

        f32x4 acc = (f32x4)0.f;
#pragma unroll
        for (int i = 0; i < N_EVENTS; ++i) {
            acc += (offs[i] >= 0) ? vals[i] : (f32x4)0.f;
        }

        __builtin_nontemporal_store(acc, reinterpret_cast<f32x4*>(ob + s0));
    }
}

extern "C" void kernel_launch(void* const* d_in, const int* in_sizes, int n_in,
                              void* d_out, int out_size, void* d_ws, size_t ws_size,
                              hipStream_t stream) {
    const float* x       = (const float*)d_in[0];
    const int*   indices = (const int*)d_in[1];
    float*       out     = (float*)d_out;

    // 128 batches * 8 tile-quads = 1024 blocks
    ola_gather_kernel<<<1024, 256, 0, stream>>>(x, indices, out);
}